// Round 2
// baseline (1538.710 us; speedup 1.0000x reference)
//
#include <hip/hip_runtime.h>

// ---------- types & helpers ----------
typedef __bf16 v8bf __attribute__((ext_vector_type(8)));
typedef float  v4f  __attribute__((ext_vector_type(4)));

__device__ __forceinline__ float bf2f(unsigned short h) {
    union { unsigned int u; float f; } x; x.u = ((unsigned int)h) << 16; return x.f;
}
__device__ __forceinline__ unsigned short f2bf(float f) {
    union { float f; unsigned int u; } x; x.f = f;
    unsigned int u = x.u;
    u += 0x7fffu + ((u >> 16) & 1u);           // RNE
    return (unsigned short)(u >> 16);
}
// async global->LDS, 16B per lane. LDS dest must be wave-uniform base + lane*16.
__device__ __forceinline__ void gll16(const void* g, void* l) {
    __builtin_amdgcn_global_load_lds((__attribute__((address_space(1))) void*)g,
                                     (__attribute__((address_space(3))) void*)l,
                                     16, 0, 0);
}

// ---------- fp32 -> bf16 elementwise convert (x) ----------
__global__ __launch_bounds__(256) void cvt_f32_bf16(
    const float* __restrict__ in, unsigned short* __restrict__ out)
{
    size_t i = ((size_t)blockIdx.x * 256 + threadIdx.x) * 4;
    float4 v = *(const float4*)&in[i];
    ushort4 o;
    o.x = f2bf(v.x); o.y = f2bf(v.y); o.z = f2bf(v.z); o.w = f2bf(v.w);
    *(ushort4*)&out[i] = o;
}

// ---------- fp32 -> bf16 transposing convert (weights), 64x64 tiles ----------
// out[c][r] = bf16(in[r][c]); in row-stride ldIn, out row-stride M (=4096 rows of in)
__global__ __launch_bounds__(256) void transpose_f32_bf16(
    const float* __restrict__ in, unsigned short* __restrict__ out, int ldIn, int M)
{
    __shared__ unsigned short t[64][68];
    const int c0 = blockIdx.x * 64, r0 = blockIdx.y * 64;
    const int lr = threadIdx.x >> 4;           // 0..15
    const int lc = (threadIdx.x & 15) * 4;     // 0..60
#pragma unroll
    for (int i = 0; i < 4; ++i) {
        int row = lr + i * 16;
        float4 v = *(const float4*)&in[(size_t)(r0 + row) * ldIn + c0 + lc];
        ushort4 o;
        o.x = f2bf(v.x); o.y = f2bf(v.y); o.z = f2bf(v.z); o.w = f2bf(v.w);
        *(ushort4*)&t[row][lc] = o;
    }
    __syncthreads();
#pragma unroll
    for (int i = 0; i < 4; ++i) {
        int orow = lr + i * 16;                // = original col
        ushort4 v;
        v.x = t[lc + 0][orow]; v.y = t[lc + 1][orow];
        v.z = t[lc + 2][orow]; v.w = t[lc + 3][orow];
        *(ushort4*)&out[(size_t)(c0 + orow) * M + r0 + lc] = v;
    }
}

// ---------- bf16 -> bf16 batched transpose (V -> V^T) ----------
__global__ __launch_bounds__(256) void transpose_bf16(
    const unsigned short* __restrict__ in, unsigned short* __restrict__ out,
    int M, int N, long long inStride, long long outStride)
{
    __shared__ unsigned short t[64][68];
    const unsigned short* ib = in  + (long long)blockIdx.z * inStride;
    unsigned short*       ob = out + (long long)blockIdx.z * outStride;
    const int c0 = blockIdx.x * 64, r0 = blockIdx.y * 64;
    const int lr = threadIdx.x >> 4;
    const int lc = (threadIdx.x & 15) * 4;
#pragma unroll
    for (int i = 0; i < 4; ++i) {
        int row = lr + i * 16;
        ushort4 v = *(const ushort4*)&ib[(size_t)(r0 + row) * N + c0 + lc];
        *(ushort4*)&t[row][lc] = v;
    }
    __syncthreads();
#pragma unroll
    for (int i = 0; i < 4; ++i) {
        int orow = lr + i * 16;
        ushort4 v;
        v.x = t[lc + 0][orow]; v.y = t[lc + 1][orow];
        v.z = t[lc + 2][orow]; v.w = t[lc + 3][orow];
        *(ushort4*)&ob[(size_t)(c0 + orow) * M + r0 + lc] = v;
    }
}

// ---------- m97-style GEMM: C[M,N] = A[M,K] * Bt[N,K]^T (all bf16 operands) ----------
// MODE 0: store fp32 into Cf[M,N]. MODE 1: bf16 scatter into Qv [b,h,s,d] (N=4096).
template <int MODE>
__global__ __launch_bounds__(256) void gemm_bt(
    const unsigned short* __restrict__ A, const unsigned short* __restrict__ Bt,
    float* __restrict__ Cf, unsigned short* __restrict__ Qv,
    int M, int N, int K)
{
    __shared__ unsigned short lA[128 * 32];
    __shared__ unsigned short lB[128 * 32];
    const int tid  = threadIdx.x;
    const int wave = tid >> 6, lane = tid & 63;
    const int quad = lane >> 4, l16 = lane & 15;
    const int m0 = blockIdx.y * 128, n0 = blockIdx.x * 128;
    const int wm = (wave >> 1) * 64, wn = (wave & 1) * 64;

    v4f acc[4][4] = {};

    const unsigned short* Ab = A  + (size_t)(m0 + (tid >> 2)) * K + (tid & 3) * 8;
    const unsigned short* Bb = Bt + (size_t)(n0 + (tid >> 2)) * K + (tid & 3) * 8;

    for (int kt = 0; kt < K; kt += 32) {
        __syncthreads();
        gll16(Ab + kt,                   &lA[tid * 8]);
        gll16(Ab + (size_t)64 * K + kt,  &lA[2048 + tid * 8]);
        gll16(Bb + kt,                   &lB[tid * 8]);
        gll16(Bb + (size_t)64 * K + kt,  &lB[2048 + tid * 8]);
        __syncthreads();

        v8bf af[4], bfr[4];
#pragma unroll
        for (int i = 0; i < 4; ++i)
            af[i] = *(const v8bf*)&lA[(wm + i * 16 + l16) * 32 + quad * 8];
#pragma unroll
        for (int j = 0; j < 4; ++j)
            bfr[j] = *(const v8bf*)&lB[(wn + j * 16 + l16) * 32 + quad * 8];
#pragma unroll
        for (int i = 0; i < 4; ++i)
#pragma unroll
            for (int j = 0; j < 4; ++j)
                acc[i][j] = __builtin_amdgcn_mfma_f32_16x16x32_bf16(
                    af[i], bfr[j], acc[i][j], 0, 0, 0);
    }

    // C/D layout: col = lane&15, row = quad*4 + reg  [m89-verified]
    if (MODE == 0) {
#pragma unroll
        for (int i = 0; i < 4; ++i) {
            int gm = m0 + wm + i * 16 + quad * 4;
#pragma unroll
            for (int j = 0; j < 4; ++j) {
                int gn = n0 + wn + j * 16 + l16;
#pragma unroll
                for (int r = 0; r < 4; ++r)
                    Cf[(size_t)(gm + r) * N + gn] = acc[i][j][r];
            }
        }
    } else {
        // scatter into [b=gm>>11, head=gn>>7, s=gm&2047, d=gn&127]
#pragma unroll
        for (int i = 0; i < 4; ++i) {
            int gmb = m0 + wm + i * 16 + quad * 4;
#pragma unroll
            for (int j = 0; j < 4; ++j) {
                int gn = n0 + wn + j * 16 + l16;
                int head = gn >> 7, d = gn & 127;
#pragma unroll
                for (int r = 0; r < 4; ++r) {
                    int gm = gmb + r;
                    int b = gm >> 11, s = gm & 2047;
                    Qv[((((size_t)(b * 32 + head)) << 11) + s) * 128 + d] =
                        f2bf(acc[i][j][r]);
                }
            }
        }
    }
}

// ---------- RoPE in-place on Q and K (layout [b,h,s,128], bf16) ----------
__global__ __launch_bounds__(256) void rope_kernel(unsigned short* Q, unsigned short* Kt)
{
    int idx  = blockIdx.x * 256 + threadIdx.x;   // pair index, 64 pairs per row
    int d    = idx & 63;
    int rest = idx >> 6;                          // (b*32+h)*2048 + s
    int s    = rest & 2047;
    size_t base = (size_t)rest << 7;
    float inv = powf(10000.0f, -(float)d * 0.015625f);   // 10000^(-d/64)
    float ang = (float)s * inv;
    float sn, cs;
    sincosf(ang, &sn, &cs);
    float q1 = bf2f(Q[base + d]), q2 = bf2f(Q[base + d + 64]);
    Q[base + d]      = f2bf(q1 * cs - q2 * sn);
    Q[base + d + 64] = f2bf(q2 * cs + q1 * sn);
    float k1 = bf2f(Kt[base + d]), k2 = bf2f(Kt[base + d + 64]);
    Kt[base + d]      = f2bf(k1 * cs - k2 * sn);
    Kt[base + d + 64] = f2bf(k2 * cs + k1 * sn);
}

// ---------- causal flash attention ----------
// Q,K: [b*32+h][s][128]; Vt: [b*32+h][128][s]; ctx: [(b*2048+s)][h*128+d] bf16
__global__ __launch_bounds__(256) void attn_kernel(
    const unsigned short* __restrict__ Q, const unsigned short* __restrict__ Kg,
    const unsigned short* __restrict__ Vt, unsigned short* __restrict__ ctx)
{
    __shared__ unsigned short lK[64 * 128];   // [kv][d], chunk-swizzled
    __shared__ unsigned short lV[128 * 64];   // [d][kv], chunk-swizzled
    __shared__ unsigned short lP[4][16 * 72]; // per-wave P, padded pitch 72

    const int qt  = gridDim.x - 1 - blockIdx.x;  // long blocks dispatched first
    const int bh  = blockIdx.y;
    const int tid = threadIdx.x;
    const int wave = tid >> 6, lane = tid & 63;
    const int quad = lane >> 4, l16 = lane & 15;
    const int q0 = qt * 64;
    const size_t base = (size_t)bh << 18;        // *2048*128

    // Q fragments (A-operand: m = lane&15, k = quad*8+j), rows q0+wave*16+l16
    v8bf qf[4];
    {
        const unsigned short* qrow =
            Q + base + ((size_t)(q0 + wave * 16 + l16) << 7) + quad * 8;
#pragma unroll
        for (int kc = 0; kc < 4; ++kc)
            qf[kc] = *(const v8bf*)(qrow + kc * 32);
    }

    float mrow[4], lrow[4];
    v4f Oa[8] = {};
#pragma unroll
    for (int r = 0; r < 4; ++r) { mrow[r] = -1e30f; lrow[r] = 0.f; }
    const float c2 = 0.08838834764831845f * 1.4426950408889634f; // scale*log2e

    unsigned short* Pw = &lP[wave][0];
    const int nkt = qt + 1;

    for (int kt = 0; kt < nkt; ++kt) {
        const int kv0 = kt * 64;
        __syncthreads();
        // stage K tile (64x128): 16 chunks/row, XOR-swizzled by row&15
#pragma unroll
        for (int it = 0; it < 4; ++it) {
            int cid = it * 256 + tid;
            int row = cid >> 4, chk = cid & 15;
            gll16(Kg + base + ((size_t)(kv0 + row) << 7) + ((chk ^ (row & 15)) << 3),
                  &lK[cid << 3]);
        }
        // stage Vt tile (128x64): 8 chunks/row, XOR-swizzled by row&7
#pragma unroll
        for (int it = 0; it < 4; ++it) {
            int cid = it * 256 + tid;
            int row = cid >> 3, chk = cid & 7;
            gll16(Vt + base + ((size_t)row << 11) + kv0 + ((chk ^ (row & 7)) << 3),
                  &lV[cid << 3]);
        }
        __syncthreads();

        // S = Q K^T  (D: row = q_local = quad*4+r, col = kv_local = l16)
        v4f sc[4] = {};
#pragma unroll
        for (int kc = 0; kc < 4; ++kc) {
#pragma unroll
            for (int nt = 0; nt < 4; ++nt) {
                v8bf kf = *(const v8bf*)&lK[((nt * 16 + l16) << 7) +
                                            ((((kc << 2) + quad) ^ l16) << 3)];
                sc[nt] = __builtin_amdgcn_mfma_f32_16x16x32_bf16(qf[kc], kf, sc[nt], 0, 0, 0);
            }
        }

        if (kt == qt) {  // diagonal tile: causal mask
            const int qrow = q0 + wave * 16 + quad * 4;
#pragma unroll
            for (int nt = 0; nt < 4; ++nt) {
                int kv = kv0 + nt * 16 + l16;
#pragma unroll
                for (int r = 0; r < 4; ++r)
                    if (kv > qrow + r) sc[nt][r] = -1e30f;
            }
        }

        // online softmax (each row's 16 cols live in lanes quad*16..quad*16+15)
        float tmax[4];
#pragma unroll
        for (int r = 0; r < 4; ++r)
            tmax[r] = fmaxf(fmaxf(sc[0][r], sc[1][r]), fmaxf(sc[2][r], sc[3][r]));
#pragma unroll
        for (int off = 1; off < 16; off <<= 1)
#pragma unroll
            for (int r = 0; r < 4; ++r)
                tmax[r] = fmaxf(tmax[r], __shfl_xor(tmax[r], off));

        float alpha[4], rsum[4];
#pragma unroll
        for (int r = 0; r < 4; ++r) {
            float mnew = fmaxf(mrow[r], tmax[r]);
            alpha[r] = exp2f((mrow[r] - mnew) * c2);
            mrow[r] = mnew;
            rsum[r] = 0.f;
        }
#pragma unroll
        for (int nt = 0; nt < 4; ++nt)
#pragma unroll
            for (int r = 0; r < 4; ++r) {
                float p = exp2f((sc[nt][r] - mrow[r]) * c2);
                sc[nt][r] = p;
                rsum[r] += p;
            }
#pragma unroll
        for (int off = 1; off < 16; off <<= 1)
#pragma unroll
            for (int r = 0; r < 4; ++r)
                rsum[r] += __shfl_xor(rsum[r], off);
#pragma unroll
        for (int r = 0; r < 4; ++r)
            lrow[r] = lrow[r] * alpha[r] + rsum[r];
#pragma unroll
        for (int d8 = 0; d8 < 8; ++d8)
#pragma unroll
            for (int r = 0; r < 4; ++r)
                Oa[d8][r] *= alpha[r];

        // P: C-layout -> LDS -> A-layout (per-wave buffer; fence orders the
        // type-punned ushort write vs v8bf read against TBAA reordering)
#pragma unroll
        for (int nt = 0; nt < 4; ++nt)
#pragma unroll
            for (int r = 0; r < 4; ++r)
                Pw[(quad * 4 + r) * 72 + nt * 16 + l16] = f2bf(sc[nt][r]);
        __threadfence_block();

#pragma unroll
        for (int kc = 0; kc < 2; ++kc) {
            v8bf pf = *(const v8bf*)&Pw[l16 * 72 + kc * 32 + quad * 8];
#pragma unroll
            for (int dt = 0; dt < 8; ++dt) {
                v8bf vf = *(const v8bf*)&lV[((dt * 16 + l16) << 6) +
                                            ((((kc << 2) + quad) ^ (l16 & 7)) << 3)];
                Oa[dt] = __builtin_amdgcn_mfma_f32_16x16x32_bf16(pf, vf, Oa[dt], 0, 0, 0);
            }
        }
    }

    // epilogue: ctx[(b*2048+q)*4096 + h*128 + d]
    const int b = bh >> 5, h = bh & 31;
    float invl[4];
#pragma unroll
    for (int r = 0; r < 4; ++r) invl[r] = 1.0f / lrow[r];
    size_t rowb = ((size_t)(b * 2048 + q0 + wave * 16 + quad * 4) << 12) + (h << 7);
#pragma unroll
    for (int dt = 0; dt < 8; ++dt)
#pragma unroll
        for (int r = 0; r < 4; ++r)
            ctx[rowb + ((size_t)r << 12) + dt * 16 + l16] = f2bf(Oa[dt][r] * invl[r]);
}

// ---------- launch ----------
extern "C" void kernel_launch(void* const* d_in, const int* in_sizes, int n_in,
                              void* d_out, int out_size, void* d_ws, size_t ws_size,
                              hipStream_t stream)
{
    const float* x    = (const float*)d_in[0];   // (2,2048,4096) fp32
    const float* Wqkv = (const float*)d_in[1];   // (4096,12288)  fp32
    const float* Wo   = (const float*)d_in[2];   // (4096,4096)   fp32
    float* out = (float*)d_out;                  // (2,2048,4096) fp32

    char* ws = (char*)d_ws;
    const size_t B32 = (size_t)32 * 1024 * 1024;   // 32 MiB = 4096*4096*2
    unsigned short* B0 = (unsigned short*)(ws);              // xb, later V^T
    unsigned short* B1 = (unsigned short*)(ws + 1 * B32);    // Q
    unsigned short* B2 = (unsigned short*)(ws + 2 * B32);    // K
    unsigned short* B3 = (unsigned short*)(ws + 3 * B32);    // V, later ctx
    unsigned short* B4 = (unsigned short*)(ws + 4 * B32);    // Wt chunk, later Wo^T
    // total ws use: 160 MiB

    // 1. x -> bf16
    cvt_f32_bf16<<<16384, 256, 0, stream>>>(x, B0);
    // 2. per chunk r: Wqkv[:, r*4096:(r+1)*4096]^T -> B4 (bf16), then GEMM -> Q/K/V
    unsigned short* qkv_dst[3] = { B1, B2, B3 };
    for (int r = 0; r < 3; ++r) {
        transpose_f32_bf16<<<dim3(64, 64), 256, 0, stream>>>(
            Wqkv + (size_t)r * 4096, B4, 12288, 4096);
        gemm_bt<1><<<dim3(32, 32), 256, 0, stream>>>(
            B0, B4, nullptr, qkv_dst[r], 4096, 4096, 4096);
    }
    // 3. RoPE on Q, K
    rope_kernel<<<32768, 256, 0, stream>>>(B1, B2);
    // 4. V -> V^T per (b,h): 64 batches of 2048x128 -> 128x2048 (into B0; xb dead)
    transpose_bf16<<<dim3(2, 32, 64), 256, 0, stream>>>(B3, B0, 2048, 128,
                                                        2048 * 128, 2048 * 128);
    // 5. Wo^T -> B4 (bf16)
    transpose_f32_bf16<<<dim3(64, 64), 256, 0, stream>>>(Wo, B4, 4096, 4096);
    // 6. flash attention -> ctx (B3; V dead after transpose)
    attn_kernel<<<dim3(32, 64), 256, 0, stream>>>(B1, B2, B0, B3);
    // 7. output projection: ctx * Wo -> fp32 out
    gemm_bt<0><<<dim3(32, 32), 256, 0, stream>>>(B3, B4, out, nullptr,
                                                 4096, 4096, 4096);
}

// Round 3
// 1499.841 us; speedup vs baseline: 1.0259x; 1.0259x over previous
//
#include <hip/hip_runtime.h>

// ---------- types & helpers ----------
typedef __bf16 v8bf __attribute__((ext_vector_type(8)));
typedef float  v4f  __attribute__((ext_vector_type(4)));

__device__ __forceinline__ float bf2f(unsigned short h) {
    union { unsigned int u; float f; } x; x.u = ((unsigned int)h) << 16; return x.f;
}
__device__ __forceinline__ unsigned short f2bf(float f) {
    union { float f; unsigned int u; } x; x.f = f;
    unsigned int u = x.u;
    u += 0x7fffu + ((u >> 16) & 1u);           // RNE
    return (unsigned short)(u >> 16);
}
// async global->LDS, 16B per lane. LDS dest must be wave-uniform base + lane*16.
__device__ __forceinline__ void gll16(const void* g, void* l) {
    __builtin_amdgcn_global_load_lds((__attribute__((address_space(1))) void*)g,
                                     (__attribute__((address_space(3))) void*)l,
                                     16, 0, 0);
}

// ---------- fp32 -> bf16 elementwise convert (x) ----------
__global__ __launch_bounds__(256) void cvt_f32_bf16(
    const float* __restrict__ in, unsigned short* __restrict__ out)
{
    size_t i = ((size_t)blockIdx.x * 256 + threadIdx.x) * 4;
    float4 v = *(const float4*)&in[i];
    ushort4 o;
    o.x = f2bf(v.x); o.y = f2bf(v.y); o.z = f2bf(v.z); o.w = f2bf(v.w);
    *(ushort4*)&out[i] = o;
}

// ---------- fp32 -> bf16 transposing convert (weights), 64x64 tiles ----------
__global__ __launch_bounds__(256) void transpose_f32_bf16(
    const float* __restrict__ in, unsigned short* __restrict__ out, int ldIn, int M)
{
    __shared__ unsigned short t[64][68];
    const int c0 = blockIdx.x * 64, r0 = blockIdx.y * 64;
    const int lr = threadIdx.x >> 4;
    const int lc = (threadIdx.x & 15) * 4;
#pragma unroll
    for (int i = 0; i < 4; ++i) {
        int row = lr + i * 16;
        float4 v = *(const float4*)&in[(size_t)(r0 + row) * ldIn + c0 + lc];
        ushort4 o;
        o.x = f2bf(v.x); o.y = f2bf(v.y); o.z = f2bf(v.z); o.w = f2bf(v.w);
        *(ushort4*)&t[row][lc] = o;
    }
    __syncthreads();
#pragma unroll
    for (int i = 0; i < 4; ++i) {
        int orow = lr + i * 16;
        ushort4 v;
        v.x = t[lc + 0][orow]; v.y = t[lc + 1][orow];
        v.z = t[lc + 2][orow]; v.w = t[lc + 3][orow];
        *(ushort4*)&out[(size_t)(c0 + orow) * M + r0 + lc] = v;
    }
}

// ---------- GEMM: C[M,N] = A[M,K] * Bt[N,K]^T (bf16 in, fp32 acc) ----------
// Wave map: each wave owns 32 m-rows (2 tiles) x full 128 n (8 tiles) so that
// RoPE pairs (d, d+64) = (acc[i][j], acc[i][j+4]) sit in the SAME lane.
// MODE 0: fp32 store to Cf[M,N].
// MODE 1: RoPE + postScale, bf16 scatter into Ov=[b,h,s,d]      (N=4096)
// MODE 2: bf16 scatter into Ov=V^T [b,h,d,s]                    (N=4096)
template <int MODE>
__global__ __launch_bounds__(256) void gemm_bt(
    const unsigned short* __restrict__ A, const unsigned short* __restrict__ Bt,
    float* __restrict__ Cf, unsigned short* __restrict__ Ov,
    float postScale, int M, int N, int K)
{
    __shared__ unsigned short lA[128 * 32];
    __shared__ unsigned short lB[128 * 32];
    const int tid  = threadIdx.x;
    const int wave = tid >> 6, lane = tid & 63;
    const int quad = lane >> 4, l16 = lane & 15;
    const int m0 = blockIdx.y * 128, n0 = blockIdx.x * 128;

    v4f acc[2][8] = {};

    const unsigned short* Ab = A  + (size_t)(m0 + (tid >> 2)) * K + (tid & 3) * 8;
    const unsigned short* Bb = Bt + (size_t)(n0 + (tid >> 2)) * K + (tid & 3) * 8;

    for (int kt = 0; kt < K; kt += 32) {
        __syncthreads();
        gll16(Ab + kt,                   &lA[tid * 8]);
        gll16(Ab + (size_t)64 * K + kt,  &lA[2048 + tid * 8]);
        gll16(Bb + kt,                   &lB[tid * 8]);
        gll16(Bb + (size_t)64 * K + kt,  &lB[2048 + tid * 8]);
        __syncthreads();

        v8bf af[2], bfr[8];
#pragma unroll
        for (int i = 0; i < 2; ++i)
            af[i] = *(const v8bf*)&lA[(wave * 32 + i * 16 + l16) * 32 + quad * 8];
#pragma unroll
        for (int j = 0; j < 8; ++j)
            bfr[j] = *(const v8bf*)&lB[(j * 16 + l16) * 32 + quad * 8];
#pragma unroll
        for (int i = 0; i < 2; ++i)
#pragma unroll
            for (int j = 0; j < 8; ++j)
                acc[i][j] = __builtin_amdgcn_mfma_f32_16x16x32_bf16(
                    af[i], bfr[j], acc[i][j], 0, 0, 0);
    }

    // C/D layout: col = lane&15, row = quad*4 + reg  [m89-verified]
    if (MODE == 0) {
#pragma unroll
        for (int i = 0; i < 2; ++i) {
            int gm = m0 + wave * 32 + i * 16 + quad * 4;
#pragma unroll
            for (int j = 0; j < 8; ++j) {
                int gn = n0 + j * 16 + l16;
#pragma unroll
                for (int r = 0; r < 4; ++r)
                    Cf[(size_t)(gm + r) * N + gn] = acc[i][j][r];
            }
        }
    } else if (MODE == 1) {
        // RoPE: out[d]    = x[d]*cos - x[d+64]*sin        (d < 64)
        //       out[d+64] = x[d+64]*cos + x[d]*sin
        const int head = n0 >> 7;                  // 128-wide n-tile = 1 head
#pragma unroll
        for (int i = 0; i < 2; ++i) {
            int gmb = m0 + wave * 32 + i * 16 + quad * 4;
            int b = gmb >> 11;
            size_t hb = ((size_t)(b * 32 + head)) << 11;
#pragma unroll
            for (int j = 0; j < 4; ++j) {
                int d1 = j * 16 + l16;             // 0..63
                float inv = powf(10000.0f, -(float)d1 * 0.015625f);
#pragma unroll
                for (int r = 0; r < 4; ++r) {
                    int s = (gmb + r) & 2047;
                    float ang = (float)s * inv, sn, cs;
                    sincosf(ang, &sn, &cs);
                    float x1 = acc[i][j][r], x2 = acc[i][j + 4][r];
                    size_t a = (hb + s) << 7;
                    Ov[a + d1]      = f2bf((x1 * cs - x2 * sn) * postScale);
                    Ov[a + d1 + 64] = f2bf((x2 * cs + x1 * sn) * postScale);
                }
            }
        }
    } else {
        // V^T: Ov[bh][d][s], s contiguous -> pack 4 rows as ushort4
        const int head = n0 >> 7;
#pragma unroll
        for (int i = 0; i < 2; ++i) {
            int gmb = m0 + wave * 32 + i * 16 + quad * 4;
            int b = gmb >> 11, s0 = gmb & 2047;
            size_t bb = ((size_t)(b * 32 + head)) << 18;   // *128*2048
#pragma unroll
            for (int j = 0; j < 8; ++j) {
                int d = j * 16 + l16;
                ushort4 o;
                o.x = f2bf(acc[i][j][0]); o.y = f2bf(acc[i][j][1]);
                o.z = f2bf(acc[i][j][2]); o.w = f2bf(acc[i][j][3]);
                *(ushort4*)&Ov[bb + ((size_t)d << 11) + s0] = o;
            }
        }
    }
}

// ---------- causal flash attention (double-buffered K/V prefetch) ----------
// Q,K: [b*32+h][s][128] (Q pre-scaled by 1/sqrt(128)); Vt: [b*32+h][128][s];
// ctx out: [(b*2048+s)][h*128+d] bf16
__global__ __launch_bounds__(256) void attn_kernel(
    const unsigned short* __restrict__ Q, const unsigned short* __restrict__ Kg,
    const unsigned short* __restrict__ Vt, unsigned short* __restrict__ ctx)
{
    __shared__ unsigned short lK[2][64 * 128];   // [kv][d], chunk-swizzled
    __shared__ unsigned short lV[2][128 * 64];   // [d][kv], chunk-swizzled
    __shared__ unsigned short lP[4][16 * 72];    // per-wave P, padded pitch 72

    const int qt  = gridDim.x - 1 - blockIdx.x;  // long blocks dispatched first
    const int bh  = blockIdx.y;
    const int tid = threadIdx.x;
    const int wave = tid >> 6, lane = tid & 63;
    const int quad = lane >> 4, l16 = lane & 15;
    const int q0 = qt * 64;
    const size_t base = (size_t)bh << 18;        // *2048*128

    // stage one 64-kv tile (K 64x128 + Vt 128x64) into buffer `buf`
    auto stage = [&](int kv0, int buf) {
#pragma unroll
        for (int it = 0; it < 4; ++it) {
            int cid = it * 256 + tid;
            int row = cid >> 4, chk = cid & 15;
            gll16(Kg + base + ((size_t)(kv0 + row) << 7) + ((chk ^ (row & 15)) << 3),
                  &lK[buf][cid << 3]);
        }
#pragma unroll
        for (int it = 0; it < 4; ++it) {
            int cid = it * 256 + tid;
            int row = cid >> 3, chk = cid & 7;
            gll16(Vt + base + ((size_t)row << 11) + kv0 + ((chk ^ (row & 7)) << 3),
                  &lV[buf][cid << 3]);
        }
    };

    // Q fragments (A-operand: m = lane&15, k = quad*8+j), rows q0+wave*16+l16
    v8bf qf[4];
    {
        const unsigned short* qrow =
            Q + base + ((size_t)(q0 + wave * 16 + l16) << 7) + quad * 8;
#pragma unroll
        for (int kc = 0; kc < 4; ++kc)
            qf[kc] = *(const v8bf*)(qrow + kc * 32);
    }

    float mrow[4], lrow[4];
    v4f Oa[8] = {};
#pragma unroll
    for (int r = 0; r < 4; ++r) { mrow[r] = -1e30f; lrow[r] = 0.f; }
    const float c2 = 1.4426950408889634f;        // log2(e); scale folded into Q

    unsigned short* Pw = &lP[wave][0];
    const int nkt = qt + 1;

    stage(0, 0);
    for (int kt = 0; kt < nkt; ++kt) {
        const int cur = kt & 1;
        // barrier: (a) compiler-emitted vmcnt(0) completes tile kt's loads,
        // (b) all waves done reading buf cur^1 -> safe to prefetch into it
        __syncthreads();
        if (kt + 1 < nkt) stage((kt + 1) * 64, cur ^ 1);  // flies during compute

        const unsigned short* K_ = &lK[cur][0];
        const unsigned short* V_ = &lV[cur][0];
        const int kv0 = kt * 64;

        // S = Q K^T  (D: row = q_local = quad*4+r, col = kv_local = l16)
        v4f sc[4] = {};
#pragma unroll
        for (int kc = 0; kc < 4; ++kc) {
#pragma unroll
            for (int nt = 0; nt < 4; ++nt) {
                v8bf kf = *(const v8bf*)&K_[((nt * 16 + l16) << 7) +
                                            ((((kc << 2) + quad) ^ l16) << 3)];
                sc[nt] = __builtin_amdgcn_mfma_f32_16x16x32_bf16(qf[kc], kf, sc[nt], 0, 0, 0);
            }
        }

        if (kt == qt) {  // diagonal tile: causal mask
            const int qrow = q0 + wave * 16 + quad * 4;
#pragma unroll
            for (int nt = 0; nt < 4; ++nt) {
                int kv = kv0 + nt * 16 + l16;
#pragma unroll
                for (int r = 0; r < 4; ++r)
                    if (kv > qrow + r) sc[nt][r] = -1e30f;
            }
        }

        // online softmax (row's 16 cols live in lanes quad*16..quad*16+15)
        float tmax[4];
#pragma unroll
        for (int r = 0; r < 4; ++r)
            tmax[r] = fmaxf(fmaxf(sc[0][r], sc[1][r]), fmaxf(sc[2][r], sc[3][r]));
#pragma unroll
        for (int off = 1; off < 16; off <<= 1)
#pragma unroll
            for (int r = 0; r < 4; ++r)
                tmax[r] = fmaxf(tmax[r], __shfl_xor(tmax[r], off));

        float alpha[4], rsum[4], mc[4];
#pragma unroll
        for (int r = 0; r < 4; ++r) {
            float mnew = fmaxf(mrow[r], tmax[r]);
            alpha[r] = exp2f((mrow[r] - mnew) * c2);
            mrow[r] = mnew;
            mc[r] = mnew * c2;
            rsum[r] = 0.f;
        }
#pragma unroll
        for (int nt = 0; nt < 4; ++nt)
#pragma unroll
            for (int r = 0; r < 4; ++r) {
                float p = exp2f(fmaf(sc[nt][r], c2, -mc[r]));
                sc[nt][r] = p;
                rsum[r] += p;
            }
#pragma unroll
        for (int off = 1; off < 16; off <<= 1)
#pragma unroll
            for (int r = 0; r < 4; ++r)
                rsum[r] += __shfl_xor(rsum[r], off);
#pragma unroll
        for (int r = 0; r < 4; ++r)
            lrow[r] = lrow[r] * alpha[r] + rsum[r];
#pragma unroll
        for (int d8 = 0; d8 < 8; ++d8)
#pragma unroll
            for (int r = 0; r < 4; ++r)
                Oa[d8][r] *= alpha[r];

        // P: C-layout -> LDS -> A-layout (per-wave buffer; fence vs TBAA)
#pragma unroll
        for (int nt = 0; nt < 4; ++nt)
#pragma unroll
            for (int r = 0; r < 4; ++r)
                Pw[(quad * 4 + r) * 72 + nt * 16 + l16] = f2bf(sc[nt][r]);
        __threadfence_block();

#pragma unroll
        for (int kc = 0; kc < 2; ++kc) {
            v8bf pf = *(const v8bf*)&Pw[l16 * 72 + kc * 32 + quad * 8];
#pragma unroll
            for (int dt = 0; dt < 8; ++dt) {
                v8bf vf = *(const v8bf*)&V_[((dt * 16 + l16) << 6) +
                                            ((((kc << 2) + quad) ^ (l16 & 7)) << 3)];
                Oa[dt] = __builtin_amdgcn_mfma_f32_16x16x32_bf16(pf, vf, Oa[dt], 0, 0, 0);
            }
        }
    }

    // epilogue: ctx[(b*2048+q)*4096 + h*128 + d]
    const int b = bh >> 5, h = bh & 31;
    float invl[4];
#pragma unroll
    for (int r = 0; r < 4; ++r) invl[r] = 1.0f / lrow[r];
    size_t rowb = ((size_t)(b * 2048 + q0 + wave * 16 + quad * 4) << 12) + (h << 7);
#pragma unroll
    for (int dt = 0; dt < 8; ++dt)
#pragma unroll
        for (int r = 0; r < 4; ++r)
            ctx[rowb + ((size_t)r << 12) + dt * 16 + l16] = f2bf(Oa[dt][r] * invl[r]);
}

// ---------- launch ----------
extern "C" void kernel_launch(void* const* d_in, const int* in_sizes, int n_in,
                              void* d_out, int out_size, void* d_ws, size_t ws_size,
                              hipStream_t stream)
{
    const float* x    = (const float*)d_in[0];   // (2,2048,4096) fp32
    const float* Wqkv = (const float*)d_in[1];   // (4096,12288)  fp32
    const float* Wo   = (const float*)d_in[2];   // (4096,4096)   fp32
    float* out = (float*)d_out;                  // (2,2048,4096) fp32

    char* ws = (char*)d_ws;
    const size_t B32 = (size_t)32 * 1024 * 1024;
    unsigned short* B0 = (unsigned short*)(ws);              // xb, later ctx
    unsigned short* B1 = (unsigned short*)(ws + 1 * B32);    // Q (pre-scaled, roped)
    unsigned short* B2 = (unsigned short*)(ws + 2 * B32);    // K (roped)
    unsigned short* B3 = (unsigned short*)(ws + 3 * B32);    // V^T
    unsigned short* B4 = (unsigned short*)(ws + 4 * B32);    // weight chunk / Wo^T
    // total ws use: 160 MiB

    const float qscale = 0.08838834764831845f;   // 1/sqrt(128)

    // 1. x -> bf16
    cvt_f32_bf16<<<16384, 256, 0, stream>>>(x, B0);
    // 2. chunk 0: Q = rope(x*Wq) * qscale  -> B1 [b,h,s,d]
    transpose_f32_bf16<<<dim3(64, 64), 256, 0, stream>>>(Wqkv, B4, 12288, 4096);
    gemm_bt<1><<<dim3(32, 32), 256, 0, stream>>>(B0, B4, nullptr, B1, qscale,
                                                 4096, 4096, 4096);
    // 3. chunk 1: K = rope(x*Wk) -> B2 [b,h,s,d]
    transpose_f32_bf16<<<dim3(64, 64), 256, 0, stream>>>(Wqkv + 4096, B4, 12288, 4096);
    gemm_bt<1><<<dim3(32, 32), 256, 0, stream>>>(B0, B4, nullptr, B2, 1.0f,
                                                 4096, 4096, 4096);
    // 4. chunk 2: V^T = (x*Wv)^T -> B3 [b,h,d,s]
    transpose_f32_bf16<<<dim3(64, 64), 256, 0, stream>>>(Wqkv + 8192, B4, 12288, 4096);
    gemm_bt<2><<<dim3(32, 32), 256, 0, stream>>>(B0, B4, nullptr, B3, 1.0f,
                                                 4096, 4096, 4096);
    // 5. Wo^T -> B4
    transpose_f32_bf16<<<dim3(64, 64), 256, 0, stream>>>(Wo, B4, 4096, 4096);
    // 6. flash attention -> ctx (B0; xb dead after chunk GEMMs)
    attn_kernel<<<dim3(32, 64), 256, 0, stream>>>(B1, B2, B3, B0);
    // 7. output projection: ctx * Wo -> fp32 out
    gemm_bt<0><<<dim3(32, 32), 256, 0, stream>>>(B0, B4, out, nullptr, 1.0f,
                                                 4096, 4096, 4096);
}